// Round 1
// baseline (259.879 us; speedup 1.0000x reference)
//
#include <hip/hip_runtime.h>

#define TM 128
#define TN 128
#define BK 64

typedef __bf16 bf16x8 __attribute__((ext_vector_type(8)));
typedef float  f32x4  __attribute__((ext_vector_type(4)));

__device__ __forceinline__ unsigned short f2bf(float f) {
    unsigned int u = __float_as_uint(f);
    u = u + 0x7fffu + ((u >> 16) & 1u);   // round-to-nearest-even
    return (unsigned short)(u >> 16);
}

// ---- prep_x: x (B,1024) fp32 -> xb bf16 row-major, x2[b] = sum(x^2) (exact fp32) ----
__global__ __launch_bounds__(256) void prep_x(const float* __restrict__ x,
                                              unsigned short* __restrict__ xb,
                                              float* __restrict__ x2) {
    const int b = blockIdx.x;
    const int t = threadIdx.x;
    const float4 v = ((const float4*)(x + (size_t)b * 1024))[t];
    float sum = v.x * v.x + v.y * v.y + v.z * v.z + v.w * v.w;
    unsigned int lo = (unsigned int)f2bf(v.x) | ((unsigned int)f2bf(v.y) << 16);
    unsigned int hi = (unsigned int)f2bf(v.z) | ((unsigned int)f2bf(v.w) << 16);
    ((uint2*)(xb + (size_t)b * 1024))[t] = make_uint2(lo, hi);
    #pragma unroll
    for (int o = 32; o > 0; o >>= 1) sum += __shfl_down(sum, o, 64);
    __shared__ float red[4];
    if ((t & 63) == 0) red[t >> 6] = sum;
    __syncthreads();
    if (t == 0) x2[b] = red[0] + red[1] + red[2] + red[3];
}

// ---- init_s: s[c] = bias[c] (c2 accumulated atomically by prep_w) ----
__global__ __launch_bounds__(256) void init_s(const float* __restrict__ bias,
                                              float* __restrict__ s, int C) {
    int i = blockIdx.x * 256 + threadIdx.x;
    if (i < C) s[i] = bias[i];
}

// ---- prep_w: cent[4q+r][d] = W[r*1024+d][q]; cb = cent in bf16 (C x D row-major);
//      s[c] += ||cent_c||^2 (fp32, from fp32 W). LDS-tiled transpose, coalesced reads.
__global__ __launch_bounds__(256) void prep_w(const float* __restrict__ W,
                                              unsigned short* __restrict__ cb,
                                              float* __restrict__ s) {
    __shared__ float tile[64][65];   // +1 pad: conflict-free column reads
    __shared__ float cred[4][64];
    const int tid = threadIdx.x;
    const int tx = tid & 63;
    const int ty = tid >> 6;
    const int q0 = blockIdx.x * 64;      // 16 q-tiles
    const int e0 = blockIdx.y * 64;      // 64 e-tiles, e = r*1024 + d
    const int r  = e0 >> 10;
    const int d0 = e0 & 1023;

    float csum = 0.f;
    #pragma unroll
    for (int p = 0; p < 16; p++) {
        const int er = p * 4 + ty;
        const float v = W[(size_t)(e0 + er) * 1024 + q0 + tx];
        tile[er][tx] = v;
        csum += v * v;
    }
    cred[ty][tx] = csum;
    __syncthreads();
    if (ty == 0) {
        atomicAdd(&s[4 * (q0 + tx) + r],
                  cred[0][tx] + cred[1][tx] + cred[2][tx] + cred[3][tx]);
    }
    #pragma unroll
    for (int p = 0; p < 16; p++) {
        const int q = q0 + p * 4 + ty;
        const float v = tile[tx][p * 4 + ty];
        cb[(size_t)(4 * q + r) * 1024 + d0 + tx] = f2bf(v);
    }
}

// ---- gemm_bt: out[m][n] = 2*sum_k A[m][k]*Bt[n][k] - x2[m] - s[n] ----
// m97 structure: 128x128 tile, 4 waves (2x2), 4x4 16x16x32 bf16 MFMA per wave,
// BK=64, global_load_lds width=16 staging, 2-barrier K-loop.
__global__ __launch_bounds__(256) void gemm_bt(const unsigned short* __restrict__ A,
                                               const unsigned short* __restrict__ Bt,
                                               const float* __restrict__ x2,
                                               const float* __restrict__ s,
                                               float* __restrict__ out,
                                               int M, int N, int K) {
    __shared__ unsigned short la[TM * BK];   // 16 KB
    __shared__ unsigned short lb[TN * BK];   // 16 KB

    const int tid  = threadIdx.x;
    const int wave = tid >> 6;
    const int lane = tid & 63;
    const int quad = lane >> 4;
    const int l16  = lane & 15;
    const int wm   = wave & 1;     // 2x2 wave grid -> 64x64 per wave
    const int wn   = wave >> 1;

    const int tile_m = blockIdx.y * TM;
    const int tile_n = blockIdx.x * TN;

    // staging: lane covers row (base + lane/8), k = (lane&7)*8; LDS dest = base + lane*16B
    const int srow = lane >> 3;
    const int scol = (lane & 7) * 8;
    const unsigned short* gA = A  + (size_t)(tile_m + wave * 32 + srow) * K + scol;
    const unsigned short* gB = Bt + (size_t)(tile_n + wave * 32 + srow) * K + scol;

    f32x4 acc[4][4];
    #pragma unroll
    for (int i = 0; i < 4; i++)
        #pragma unroll
        for (int j = 0; j < 4; j++) acc[i][j] = (f32x4){0.f, 0.f, 0.f, 0.f};

    for (int kt = 0; kt < K; kt += BK) {
        __syncthreads();   // previous tile's reads done before overwrite
        #pragma unroll
        for (int i = 0; i < 4; i++) {
            __builtin_amdgcn_global_load_lds(
                (const __attribute__((address_space(1))) void*)(gA + (size_t)(i * 8) * K + kt),
                (__attribute__((address_space(3))) void*)(la + (wave * 32 + i * 8) * BK),
                16, 0, 0);
            __builtin_amdgcn_global_load_lds(
                (const __attribute__((address_space(1))) void*)(gB + (size_t)(i * 8) * K + kt),
                (__attribute__((address_space(3))) void*)(lb + (wave * 32 + i * 8) * BK),
                16, 0, 0);
        }
        __syncthreads();   // compiler emits vmcnt(0) drain before s_barrier

        const unsigned short* pa = la + (wm * 64 + l16) * BK + quad * 8;
        const unsigned short* pb = lb + (wn * 64 + l16) * BK + quad * 8;
        #pragma unroll
        for (int ks = 0; ks < BK; ks += 32) {
            bf16x8 af[4], bf[4];
            #pragma unroll
            for (int i = 0; i < 4; i++) af[i] = *(const bf16x8*)(pa + i * 16 * BK + ks);
            #pragma unroll
            for (int j = 0; j < 4; j++) bf[j] = *(const bf16x8*)(pb + j * 16 * BK + ks);
            #pragma unroll
            for (int i = 0; i < 4; i++)
                #pragma unroll
                for (int j = 0; j < 4; j++)
                    acc[i][j] = __builtin_amdgcn_mfma_f32_16x16x32_bf16(af[i], bf[j], acc[i][j], 0, 0, 0);
        }
    }

    // epilogue: C/D layout col = lane&15, row = quad*4 + reg
    #pragma unroll
    for (int j = 0; j < 4; j++) {
        const int n = tile_n + wn * 64 + j * 16 + l16;
        const float sn = s[n];
        #pragma unroll
        for (int i = 0; i < 4; i++) {
            const int mb = tile_m + wm * 64 + i * 16 + quad * 4;
            const f32x4 xv = *(const f32x4*)(x2 + mb);
            #pragma unroll
            for (int rr = 0; rr < 4; rr++) {
                out[(size_t)(mb + rr) * N + n] = 2.f * acc[i][j][rr] - xv[rr] - sn;
            }
        }
    }
}

extern "C" void kernel_launch(void* const* d_in, const int* in_sizes, int n_in,
                              void* d_out, int out_size, void* d_ws, size_t ws_size,
                              hipStream_t stream) {
    const float* x    = (const float*)d_in[0];
    const float* w    = (const float*)d_in[1];
    const float* bias = (const float*)d_in[2];
    float* out = (float*)d_out;

    const int C = in_sizes[2];              // 4096
    const int D = in_sizes[1] / C;          // 1024
    const int B = in_sizes[0] / D;          // 8192

    unsigned short* xb = (unsigned short*)d_ws;            // B*D bf16 = 16 MB
    unsigned short* cb = xb + (size_t)B * D;               // C*D bf16 = 8 MB
    float* x2 = (float*)(cb + (size_t)C * D);              // B fp32
    float* s  = x2 + B;                                    // C fp32

    init_s<<<(C + 255) / 256, 256, 0, stream>>>(bias, s, C);
    prep_w<<<dim3(D / 64, C / 64), 256, 0, stream>>>(w, cb, s);
    prep_x<<<B, 256, 0, stream>>>(x, xb, x2);
    gemm_bt<<<dim3(C / TN, B / TM), 256, 0, stream>>>(xb, cb, x2, s, out, B, C, D);
}

// Round 2
// 245.160 us; speedup vs baseline: 1.0600x; 1.0600x over previous
//
#include <hip/hip_runtime.h>

#define TM 128
#define TN 128
#define BK 64

typedef __bf16 bf16x8 __attribute__((ext_vector_type(8)));
typedef float  f32x4  __attribute__((ext_vector_type(4)));

__device__ __forceinline__ unsigned short f2bf(float f) {
    unsigned int u = __float_as_uint(f);
    u = u + 0x7fffu + ((u >> 16) & 1u);   // round-to-nearest-even
    return (unsigned short)(u >> 16);
}

// ---- prep_x: x (B,1024) fp32 -> xb bf16 row-major, x2[b] = sum(x^2) (exact fp32) ----
__global__ __launch_bounds__(256) void prep_x(const float* __restrict__ x,
                                              unsigned short* __restrict__ xb,
                                              float* __restrict__ x2) {
    const int b = blockIdx.x;
    const int t = threadIdx.x;
    const float4 v = ((const float4*)(x + (size_t)b * 1024))[t];
    float sum = v.x * v.x + v.y * v.y + v.z * v.z + v.w * v.w;
    unsigned int lo = (unsigned int)f2bf(v.x) | ((unsigned int)f2bf(v.y) << 16);
    unsigned int hi = (unsigned int)f2bf(v.z) | ((unsigned int)f2bf(v.w) << 16);
    ((uint2*)(xb + (size_t)b * 1024))[t] = make_uint2(lo, hi);
    #pragma unroll
    for (int o = 32; o > 0; o >>= 1) sum += __shfl_down(sum, o, 64);
    __shared__ float red[4];
    if ((t & 63) == 0) red[t >> 6] = sum;
    __syncthreads();
    if (t == 0) x2[b] = red[0] + red[1] + red[2] + red[3];
}

// ---- init_s: s[c] = bias[c] (c2 accumulated atomically by prep_w) ----
__global__ __launch_bounds__(256) void init_s(const float* __restrict__ bias,
                                              float* __restrict__ s, int C) {
    int i = blockIdx.x * 256 + threadIdx.x;
    if (i < C) s[i] = bias[i];
}

// ---- prep_w: cent[4q+r][d] = W[r*1024+d][q]; cb = cent in bf16 (C x D row-major);
//      s[c] += ||cent_c||^2 (fp32, from fp32 W). LDS-tiled transpose, coalesced reads.
__global__ __launch_bounds__(256) void prep_w(const float* __restrict__ W,
                                              unsigned short* __restrict__ cb,
                                              float* __restrict__ s) {
    __shared__ float tile[64][65];   // +1 pad: conflict-free column reads
    __shared__ float cred[4][64];
    const int tid = threadIdx.x;
    const int tx = tid & 63;
    const int ty = tid >> 6;
    const int q0 = blockIdx.x * 64;      // 16 q-tiles
    const int e0 = blockIdx.y * 64;      // 64 e-tiles, e = r*1024 + d
    const int r  = e0 >> 10;
    const int d0 = e0 & 1023;

    float csum = 0.f;
    #pragma unroll
    for (int p = 0; p < 16; p++) {
        const int er = p * 4 + ty;
        const float v = W[(size_t)(e0 + er) * 1024 + q0 + tx];
        tile[er][tx] = v;
        csum += v * v;
    }
    cred[ty][tx] = csum;
    __syncthreads();
    if (ty == 0) {
        atomicAdd(&s[4 * (q0 + tx) + r],
                  cred[0][tx] + cred[1][tx] + cred[2][tx] + cred[3][tx]);
    }
    #pragma unroll
    for (int p = 0; p < 16; p++) {
        const int q = q0 + p * 4 + ty;
        const float v = tile[tx][p * 4 + ty];
        cb[(size_t)(4 * q + r) * 1024 + d0 + tx] = f2bf(v);
    }
}

// ---- gemm_bt: out[m][n] = 2*sum_k A[m][k]*Bt[n][k] - x2[m] - s[n] ----
// m97 structure: 128x128 tile, 4 waves (2x2), 4x4 16x16x32 bf16 MFMA per wave,
// BK=64, global_load_lds width=16 staging, 2-barrier K-loop.
// LDS layout XOR-swizzled: slot(row,k8) = row*64 + ((k8 ^ (row&7))*8) shorts.
// Swizzle applied on the staging SOURCE side (global_load_lds dest is forced
// to base + lane*16B), and un-applied on the fragment read side. Kills the
// 16-way bank conflict of the row-stride-128B layout.
__global__ __launch_bounds__(256) void gemm_bt(const unsigned short* __restrict__ A,
                                               const unsigned short* __restrict__ Bt,
                                               const float* __restrict__ x2,
                                               const float* __restrict__ s,
                                               float* __restrict__ out,
                                               int M, int N, int K) {
    __shared__ unsigned short la[TM * BK];   // 16 KB
    __shared__ unsigned short lb[TN * BK];   // 16 KB

    const int tid  = threadIdx.x;
    const int wave = tid >> 6;
    const int lane = tid & 63;
    const int quad = lane >> 4;
    const int l16  = lane & 15;
    const int wm   = wave & 1;     // 2x2 wave grid -> 64x64 per wave
    const int wn   = wave >> 1;

    const int tile_m = blockIdx.y * TM;
    const int tile_n = blockIdx.x * TN;

    // staging: lane covers row (base + lane/8); source k-chunk is XOR-swizzled
    // so that LDS slot (lane&7) of row r holds k8 = (lane&7) ^ (r&7).
    const int srow = lane >> 3;
    const int scol = ((lane & 7) ^ (srow & 7)) * 8;
    const unsigned short* gA = A  + (size_t)(tile_m + wave * 32 + srow) * K + scol;
    const unsigned short* gB = Bt + (size_t)(tile_n + wave * 32 + srow) * K + scol;

    f32x4 acc[4][4];
    #pragma unroll
    for (int i = 0; i < 4; i++)
        #pragma unroll
        for (int j = 0; j < 4; j++) acc[i][j] = (f32x4){0.f, 0.f, 0.f, 0.f};

    const int sw = l16 & 7;                       // row&7 for all fragment rows
    const unsigned short* pa_row = la + (wm * 64 + l16) * BK;
    const unsigned short* pb_row = lb + (wn * 64 + l16) * BK;

    for (int kt = 0; kt < K; kt += BK) {
        __syncthreads();   // previous tile's reads done before overwrite
        #pragma unroll
        for (int i = 0; i < 4; i++) {
            __builtin_amdgcn_global_load_lds(
                (const __attribute__((address_space(1))) void*)(gA + (size_t)(i * 8) * K + kt),
                (__attribute__((address_space(3))) void*)(la + (wave * 32 + i * 8) * BK),
                16, 0, 0);
            __builtin_amdgcn_global_load_lds(
                (const __attribute__((address_space(1))) void*)(gB + (size_t)(i * 8) * K + kt),
                (__attribute__((address_space(3))) void*)(lb + (wave * 32 + i * 8) * BK),
                16, 0, 0);
        }
        __syncthreads();   // compiler emits vmcnt(0) drain before s_barrier

        #pragma unroll
        for (int ks = 0; ks < BK; ks += 32) {
            const int ko = (((quad + (ks >> 3)) ^ sw) << 3);   // swizzled k-chunk offset
            bf16x8 af[4], bf[4];
            #pragma unroll
            for (int i = 0; i < 4; i++) af[i] = *(const bf16x8*)(pa_row + i * 16 * BK + ko);
            #pragma unroll
            for (int j = 0; j < 4; j++) bf[j] = *(const bf16x8*)(pb_row + j * 16 * BK + ko);
            #pragma unroll
            for (int i = 0; i < 4; i++)
                #pragma unroll
                for (int j = 0; j < 4; j++)
                    acc[i][j] = __builtin_amdgcn_mfma_f32_16x16x32_bf16(af[i], bf[j], acc[i][j], 0, 0, 0);
        }
    }

    // epilogue: C/D layout col = lane&15, row = quad*4 + reg
    #pragma unroll
    for (int j = 0; j < 4; j++) {
        const int n = tile_n + wn * 64 + j * 16 + l16;
        const float sn = s[n];
        #pragma unroll
        for (int i = 0; i < 4; i++) {
            const int mb = tile_m + wm * 64 + i * 16 + quad * 4;
            const f32x4 xv = *(const f32x4*)(x2 + mb);
            #pragma unroll
            for (int rr = 0; rr < 4; rr++) {
                out[(size_t)(mb + rr) * N + n] = 2.f * acc[i][j][rr] - xv[rr] - sn;
            }
        }
    }
}

extern "C" void kernel_launch(void* const* d_in, const int* in_sizes, int n_in,
                              void* d_out, int out_size, void* d_ws, size_t ws_size,
                              hipStream_t stream) {
    const float* x    = (const float*)d_in[0];
    const float* w    = (const float*)d_in[1];
    const float* bias = (const float*)d_in[2];
    float* out = (float*)d_out;

    const int C = in_sizes[2];              // 4096
    const int D = in_sizes[1] / C;          // 1024
    const int B = in_sizes[0] / D;          // 8192

    unsigned short* xb = (unsigned short*)d_ws;            // B*D bf16 = 16 MB
    unsigned short* cb = xb + (size_t)B * D;               // C*D bf16 = 8 MB
    float* x2 = (float*)(cb + (size_t)C * D);              // B fp32
    float* s  = x2 + B;                                    // C fp32

    init_s<<<(C + 255) / 256, 256, 0, stream>>>(bias, s, C);
    prep_w<<<dim3(D / 64, C / 64), 256, 0, stream>>>(w, cb, s);
    prep_x<<<B, 256, 0, stream>>>(x, xb, x2);
    gemm_bt<<<dim3(C / TN, B / TM), 256, 0, stream>>>(xb, cb, x2, s, out, B, C, D);
}

// Round 3
// 205.446 us; speedup vs baseline: 1.2650x; 1.1933x over previous
//
#include <hip/hip_runtime.h>

#define TM 128
#define TN 128
#define BK 128   // fp8 elements (bytes) per K-slab = one 16x16x128 MFMA k-step

typedef float f32x4 __attribute__((ext_vector_type(4)));
typedef int   i32x4 __attribute__((ext_vector_type(4)));
typedef int   i32x8 __attribute__((ext_vector_type(8)));

// E8M0 scales: value = 2^(byte-127). A-scale = 2^0; B holds cent*2^6, B-scale = 2^-6.
#define SCALE_A 127
#define SCALE_B 121

__device__ __forceinline__ unsigned char f2fp8(float f) {
    int p = __builtin_amdgcn_cvt_pk_fp8_f32(f, f, 0, false);
    return (unsigned char)(p & 0xff);
}

// ---- prep_x: x (B,1024) fp32 -> x8 fp8 row-major, x2[b] = sum(x^2) (exact fp32) ----
__global__ __launch_bounds__(256) void prep_x(const float* __restrict__ x,
                                              unsigned int* __restrict__ x8,
                                              float* __restrict__ x2) {
    const int b = blockIdx.x;
    const int t = threadIdx.x;
    const float4 v = ((const float4*)(x + (size_t)b * 1024))[t];
    float sum = v.x * v.x + v.y * v.y + v.z * v.z + v.w * v.w;
    int p = __builtin_amdgcn_cvt_pk_fp8_f32(v.x, v.y, 0, false);
    p = __builtin_amdgcn_cvt_pk_fp8_f32(v.z, v.w, p, true);
    x8[(size_t)b * 256 + t] = (unsigned int)p;   // bytes: fp8(x),fp8(y),fp8(z),fp8(w)
    #pragma unroll
    for (int o = 32; o > 0; o >>= 1) sum += __shfl_down(sum, o, 64);
    __shared__ float red[4];
    if ((t & 63) == 0) red[t >> 6] = sum;
    __syncthreads();
    if (t == 0) x2[b] = red[0] + red[1] + red[2] + red[3];
}

// ---- init_s: s[c] = bias[c] (c2 accumulated atomically by prep_w) ----
__global__ __launch_bounds__(256) void init_s(const float* __restrict__ bias,
                                              float* __restrict__ s, int C) {
    int i = blockIdx.x * 256 + threadIdx.x;
    if (i < C) s[i] = bias[i];
}

// ---- prep_w: cent[4q+r][d] = W[r*1024+d][q]; c8 = fp8(cent*64) (C x D row-major);
//      s[c] += ||cent_c||^2 (exact fp32, from fp32 W). LDS-tiled transpose. ----
__global__ __launch_bounds__(256) void prep_w(const float* __restrict__ W,
                                              unsigned char* __restrict__ c8,
                                              float* __restrict__ s) {
    __shared__ float tile[64][65];
    __shared__ float cred[4][64];
    const int tid = threadIdx.x;
    const int tx = tid & 63;
    const int ty = tid >> 6;
    const int q0 = blockIdx.x * 64;
    const int e0 = blockIdx.y * 64;      // e = r*1024 + d
    const int r  = e0 >> 10;
    const int d0 = e0 & 1023;

    float csum = 0.f;
    #pragma unroll
    for (int p = 0; p < 16; p++) {
        const int er = p * 4 + ty;
        const float v = W[(size_t)(e0 + er) * 1024 + q0 + tx];
        tile[er][tx] = v;
        csum += v * v;
    }
    cred[ty][tx] = csum;
    __syncthreads();
    if (ty == 0) {
        atomicAdd(&s[4 * (q0 + tx) + r],
                  cred[0][tx] + cred[1][tx] + cred[2][tx] + cred[3][tx]);
    }
    #pragma unroll
    for (int p = 0; p < 16; p++) {
        const int q = q0 + p * 4 + ty;
        const float v = tile[tx][p * 4 + ty];
        c8[(size_t)(4 * q + r) * 1024 + d0 + tx] = f2fp8(v * 64.f);
    }
}

// ---- gemm_bt: out[m][n] = 2*sum_k A[m][k]*Bt[n][k] - x2[m] - s[n] ----
// MX-scaled fp8: 16x16x128 f8f6f4 MFMA, uniform E8M0 scales (A=2^0, B=2^-6).
// 128x128 tile, 4 waves (2x2), 4x4 MFMA tiles/wave, BK=128 bytes,
// global_load_lds width=16 staging. LDS XOR-swizzle at 16B-chunk granularity:
// slot(row, c) holds global chunk c ^ (row&7) -> conflict-free reads & writes.
__global__ __launch_bounds__(256) void gemm_bt(const unsigned char* __restrict__ A,
                                               const unsigned char* __restrict__ Bt,
                                               const float* __restrict__ x2,
                                               const float* __restrict__ s,
                                               float* __restrict__ out,
                                               int M, int N, int K) {
    __shared__ unsigned char la[TM * BK];   // 16 KB
    __shared__ unsigned char lb[TN * BK];   // 16 KB

    const int tid  = threadIdx.x;
    const int wave = tid >> 6;
    const int lane = tid & 63;
    const int quad = lane >> 4;
    const int l16  = lane & 15;
    const int wm   = wave & 1;     // 2x2 wave grid -> 64x64 per wave
    const int wn   = wave >> 1;

    const int tile_m = blockIdx.y * TM;
    const int tile_n = blockIdx.x * TN;

    // staging: lane -> row (base + lane/8), slot (lane&7); source chunk XOR-swizzled
    const int srow8 = lane >> 3;                 // 0..7
    const int gcol  = ((lane & 7) ^ srow8) * 16; // source byte offset in 128-B slab
    const unsigned char* gA = A  + (size_t)(tile_m + wave * 32 + srow8) * K + gcol;
    const unsigned char* gB = Bt + (size_t)(tile_n + wave * 32 + srow8) * K + gcol;

    f32x4 acc[4][4];
    #pragma unroll
    for (int i = 0; i < 4; i++)
        #pragma unroll
        for (int j = 0; j < 4; j++) acc[i][j] = (f32x4){0.f, 0.f, 0.f, 0.f};

    const int sw = l16 & 7;
    const int slot_lo = ((2 * quad) ^ sw) * 16;      // frag bytes 0-15  (k-block lo)
    const int slot_hi = ((2 * quad + 1) ^ sw) * 16;  // frag bytes 16-31 (k-block hi)
    const unsigned char* pa_row = la + (wm * 64 + l16) * BK;
    const unsigned char* pb_row = lb + (wn * 64 + l16) * BK;

    for (int kt = 0; kt < K; kt += BK) {
        __syncthreads();
        #pragma unroll
        for (int i = 0; i < 4; i++) {
            __builtin_amdgcn_global_load_lds(
                (const __attribute__((address_space(1))) void*)(gA + (size_t)(i * 8) * K + kt),
                (__attribute__((address_space(3))) void*)(la + (wave * 32 + i * 8) * BK),
                16, 0, 0);
            __builtin_amdgcn_global_load_lds(
                (const __attribute__((address_space(1))) void*)(gB + (size_t)(i * 8) * K + kt),
                (__attribute__((address_space(3))) void*)(lb + (wave * 32 + i * 8) * BK),
                16, 0, 0);
        }
        __syncthreads();

        i32x8 af[4], bf[4];
        #pragma unroll
        for (int i = 0; i < 4; i++) {
            i32x4 lo = *(const i32x4*)(pa_row + i * 16 * BK + slot_lo);
            i32x4 hi = *(const i32x4*)(pa_row + i * 16 * BK + slot_hi);
            af[i] = __builtin_shufflevector(lo, hi, 0, 1, 2, 3, 4, 5, 6, 7);
        }
        #pragma unroll
        for (int j = 0; j < 4; j++) {
            i32x4 lo = *(const i32x4*)(pb_row + j * 16 * BK + slot_lo);
            i32x4 hi = *(const i32x4*)(pb_row + j * 16 * BK + slot_hi);
            bf[j] = __builtin_shufflevector(lo, hi, 0, 1, 2, 3, 4, 5, 6, 7);
        }
        #pragma unroll
        for (int i = 0; i < 4; i++)
            #pragma unroll
            for (int j = 0; j < 4; j++)
                acc[i][j] = __builtin_amdgcn_mfma_scale_f32_16x16x128_f8f6f4(
                    af[i], bf[j], acc[i][j],
                    0, 0,             // cbsz=fp8(e4m3), blgp=fp8(e4m3)
                    0, SCALE_A,       // A scale: byte0, 2^0
                    0, SCALE_B);      // B scale: byte0, 2^-6
    }

    // epilogue: C/D layout col = lane&15, row = quad*4 + reg (dtype-independent)
    #pragma unroll
    for (int j = 0; j < 4; j++) {
        const int n = tile_n + wn * 64 + j * 16 + l16;
        const float sn = s[n];
        #pragma unroll
        for (int i = 0; i < 4; i++) {
            const int mb = tile_m + wm * 64 + i * 16 + quad * 4;
            const f32x4 xv = *(const f32x4*)(x2 + mb);
            #pragma unroll
            for (int rr = 0; rr < 4; rr++) {
                out[(size_t)(mb + rr) * N + n] = 2.f * acc[i][j][rr] - xv[rr] - sn;
            }
        }
    }
}

extern "C" void kernel_launch(void* const* d_in, const int* in_sizes, int n_in,
                              void* d_out, int out_size, void* d_ws, size_t ws_size,
                              hipStream_t stream) {
    const float* x    = (const float*)d_in[0];
    const float* w    = (const float*)d_in[1];
    const float* bias = (const float*)d_in[2];
    float* out = (float*)d_out;

    const int C = in_sizes[2];              // 4096
    const int D = in_sizes[1] / C;          // 1024
    const int B = in_sizes[0] / D;          // 8192

    unsigned char* x8 = (unsigned char*)d_ws;              // B*D fp8 = 8 MB
    unsigned char* c8 = x8 + (size_t)B * D;                // C*D fp8 = 4 MB
    float* x2 = (float*)(c8 + (size_t)C * D);              // B fp32
    float* s  = x2 + B;                                    // C fp32

    init_s<<<(C + 255) / 256, 256, 0, stream>>>(bias, s, C);
    prep_w<<<dim3(D / 64, C / 64), 256, 0, stream>>>(w, c8, s);
    prep_x<<<B, 256, 0, stream>>>(x, (unsigned int*)x8, x2);
    gemm_bt<<<dim3(C / TN, B / TM), 256, 0, stream>>>(x8, c8, x2, s, out, B, C, D);
}

// Round 4
// 203.895 us; speedup vs baseline: 1.2746x; 1.0076x over previous
//
#include <hip/hip_runtime.h>

#define TM 128
#define TN 128
#define BK 128   // fp8 bytes per K-slab = one 16x16x128 MFMA k-step

typedef float f32x4 __attribute__((ext_vector_type(4)));
typedef int   i32x4 __attribute__((ext_vector_type(4)));
typedef int   i32x8 __attribute__((ext_vector_type(8)));

// E8M0 scales: value = 2^(byte-127). A-scale = 2^0; B holds cent*2^6, B-scale = 2^-6.
#define SCALE_A 127
#define SCALE_B 121

__device__ __forceinline__ unsigned char f2fp8(float f) {
    int p = __builtin_amdgcn_cvt_pk_fp8_f32(f, f, 0, false);
    return (unsigned char)(p & 0xff);
}

// ---- prep_x: x (B,1024) fp32 -> x8 fp8 row-major, x2[b] = sum(x^2) (exact fp32) ----
__global__ __launch_bounds__(256) void prep_x(const float* __restrict__ x,
                                              unsigned int* __restrict__ x8,
                                              float* __restrict__ x2) {
    const int b = blockIdx.x;
    const int t = threadIdx.x;
    const float4 v = ((const float4*)(x + (size_t)b * 1024))[t];
    float sum = v.x * v.x + v.y * v.y + v.z * v.z + v.w * v.w;
    int p = __builtin_amdgcn_cvt_pk_fp8_f32(v.x, v.y, 0, false);
    p = __builtin_amdgcn_cvt_pk_fp8_f32(v.z, v.w, p, true);
    x8[(size_t)b * 256 + t] = (unsigned int)p;
    #pragma unroll
    for (int o = 32; o > 0; o >>= 1) sum += __shfl_down(sum, o, 64);
    __shared__ float red[4];
    if ((t & 63) == 0) red[t >> 6] = sum;
    __syncthreads();
    if (t == 0) x2[b] = red[0] + red[1] + red[2] + red[3];
}

// ---- init_s: s[c] = bias[c] (c2 accumulated atomically by prep_w) ----
__global__ __launch_bounds__(256) void init_s(const float* __restrict__ bias,
                                              float* __restrict__ s, int C) {
    int i = blockIdx.x * 256 + threadIdx.x;
    if (i < C) s[i] = bias[i];
}

// ---- prep_w: cent[4q+r][d] = W[r*1024+d][q]; c8 = fp8(cent*64) (C x D row-major);
//      s[c] += ||cent_c||^2 (exact fp32, from fp32 W). LDS-tiled transpose. ----
__global__ __launch_bounds__(256) void prep_w(const float* __restrict__ W,
                                              unsigned char* __restrict__ c8,
                                              float* __restrict__ s) {
    __shared__ float tile[64][65];
    __shared__ float cred[4][64];
    const int tid = threadIdx.x;
    const int tx = tid & 63;
    const int ty = tid >> 6;
    const int q0 = blockIdx.x * 64;
    const int e0 = blockIdx.y * 64;      // e = r*1024 + d
    const int r  = e0 >> 10;
    const int d0 = e0 & 1023;

    float csum = 0.f;
    #pragma unroll
    for (int p = 0; p < 16; p++) {
        const int er = p * 4 + ty;
        const float v = W[(size_t)(e0 + er) * 1024 + q0 + tx];
        tile[er][tx] = v;
        csum += v * v;
    }
    cred[ty][tx] = csum;
    __syncthreads();
    if (ty == 0) {
        atomicAdd(&s[4 * (q0 + tx) + r],
                  cred[0][tx] + cred[1][tx] + cred[2][tx] + cred[3][tx]);
    }
    #pragma unroll
    for (int p = 0; p < 16; p++) {
        const int q = q0 + p * 4 + ty;
        const float v = tile[tx][p * 4 + ty];
        c8[(size_t)(4 * q + r) * 1024 + d0 + tx] = f2fp8(v * 64.f);
    }
}

// ---- gemm_bt: out[m][n] = 2*sum_k A[m][k]*Bt[n][k] - x2[m] - s[n] ----
// MX-scaled fp8 16x16x128, 128x128 tile, 4 waves, 4x4 MFMA tiles/wave.
// PING-PONG double-buffered LDS, ONE barrier per K-slab:
//   barrier -> issue global_load_lds(next slab, other buffer) -> compute(this buffer)
// so the vmcnt(0) drain at each barrier waits on loads issued a full compute
// phase earlier. XOR-swizzled LDS chunks (conflict-free, verified R2).
// Grid is flat with XCD m-stripe swizzle: xcd = bid&7 owns 8 m-tiles (1 MB
// A-stripe resident in its 4 MB L2), B streams.
__global__ __launch_bounds__(256) void gemm_bt(const unsigned char* __restrict__ A,
                                               const unsigned char* __restrict__ Bt,
                                               const float* __restrict__ x2,
                                               const float* __restrict__ s,
                                               float* __restrict__ out,
                                               int M, int N, int K) {
    __shared__ unsigned char la0[TM * BK];   // 16 KB each, 64 KB total
    __shared__ unsigned char lb0[TN * BK];
    __shared__ unsigned char la1[TM * BK];
    __shared__ unsigned char lb1[TN * BK];

    const int tid  = threadIdx.x;
    const int wave = tid >> 6;
    const int lane = tid & 63;
    const int quad = lane >> 4;
    const int l16  = lane & 15;
    const int wm   = wave & 1;
    const int wn   = wave >> 1;

    // XCD m-stripe swizzle (M/TM = 64 m-tiles, N/TN = 32 n-tiles)
    const int flat = blockIdx.x;
    const int xcd  = flat & 7;
    const int idx  = flat >> 3;
    const int mt   = (idx & 7) | (xcd << 3);
    const int nt   = idx >> 3;
    const int tile_m = mt * TM;
    const int tile_n = nt * TN;

    // staging: lane -> row (base + lane/8), slot (lane&7); source chunk XOR-swizzled
    const int srow8 = lane >> 3;
    const int gcol  = ((lane & 7) ^ srow8) * 16;
    const unsigned char* gA = A  + (size_t)(tile_m + wave * 32 + srow8) * K + gcol;
    const unsigned char* gB = Bt + (size_t)(tile_n + wave * 32 + srow8) * K + gcol;

    f32x4 acc[4][4];
    #pragma unroll
    for (int i = 0; i < 4; i++)
        #pragma unroll
        for (int j = 0; j < 4; j++) acc[i][j] = (f32x4){0.f, 0.f, 0.f, 0.f};

    const int sw = l16 & 7;
    const int slot_lo = ((2 * quad) ^ sw) * 16;
    const int slot_hi = ((2 * quad + 1) ^ sw) * 16;
    const int rowoff_a = (wm * 64 + l16) * BK;
    const int rowoff_b = (wn * 64 + l16) * BK;
    const int stage_off = (wave * 32) * BK;

#define ISSUE_SLAB(la, lb, kt)                                                              \
    do {                                                                                    \
        _Pragma("unroll")                                                                   \
        for (int i = 0; i < 4; i++) {                                                       \
            __builtin_amdgcn_global_load_lds(                                               \
                (const __attribute__((address_space(1))) void*)(gA + (size_t)(i * 8) * K + (kt)), \
                (__attribute__((address_space(3))) void*)((la) + stage_off + i * 8 * BK),   \
                16, 0, 0);                                                                  \
            __builtin_amdgcn_global_load_lds(                                               \
                (const __attribute__((address_space(1))) void*)(gB + (size_t)(i * 8) * K + (kt)), \
                (__attribute__((address_space(3))) void*)((lb) + stage_off + i * 8 * BK),   \
                16, 0, 0);                                                                  \
        }                                                                                   \
    } while (0)

#define COMPUTE_SLAB(la, lb)                                                                \
    do {                                                                                    \
        i32x8 af[4], bf[4];                                                                 \
        _Pragma("unroll")                                                                   \
        for (int i = 0; i < 4; i++) {                                                       \
            i32x4 lo = *(const i32x4*)((la) + rowoff_a + i * 16 * BK + slot_lo);            \
            i32x4 hi = *(const i32x4*)((la) + rowoff_a + i * 16 * BK + slot_hi);            \
            af[i] = __builtin_shufflevector(lo, hi, 0, 1, 2, 3, 4, 5, 6, 7);                \
        }                                                                                   \
        _Pragma("unroll")                                                                   \
        for (int j = 0; j < 4; j++) {                                                       \
            i32x4 lo = *(const i32x4*)((lb) + rowoff_b + j * 16 * BK + slot_lo);            \
            i32x4 hi = *(const i32x4*)((lb) + rowoff_b + j * 16 * BK + slot_hi);            \
            bf[j] = __builtin_shufflevector(lo, hi, 0, 1, 2, 3, 4, 5, 6, 7);                \
        }                                                                                   \
        _Pragma("unroll")                                                                   \
        for (int i = 0; i < 4; i++)                                                         \
            _Pragma("unroll")                                                               \
            for (int j = 0; j < 4; j++)                                                     \
                acc[i][j] = __builtin_amdgcn_mfma_scale_f32_16x16x128_f8f6f4(               \
                    af[i], bf[j], acc[i][j], 0, 0, 0, SCALE_A, 0, SCALE_B);                 \
    } while (0)

    ISSUE_SLAB(la0, lb0, 0);
    for (int kt = 0; kt < K; kt += 2 * BK) {
        __syncthreads();                       // drains slab kt's loads (issued last phase)
        if (kt + BK < K) ISSUE_SLAB(la1, lb1, kt + BK);
        COMPUTE_SLAB(la0, lb0);
        __syncthreads();                       // drains slab kt+BK's loads
        if (kt + 2 * BK < K) ISSUE_SLAB(la0, lb0, kt + 2 * BK);
        COMPUTE_SLAB(la1, lb1);
    }
#undef ISSUE_SLAB
#undef COMPUTE_SLAB

    // epilogue: C/D layout col = lane&15, row = quad*4 + reg
    #pragma unroll
    for (int j = 0; j < 4; j++) {
        const int n = tile_n + wn * 64 + j * 16 + l16;
        const float sn = s[n];
        #pragma unroll
        for (int i = 0; i < 4; i++) {
            const int mb = tile_m + wm * 64 + i * 16 + quad * 4;
            const f32x4 xv = *(const f32x4*)(x2 + mb);
            #pragma unroll
            for (int rr = 0; rr < 4; rr++) {
                out[(size_t)(mb + rr) * N + n] = 2.f * acc[i][j][rr] - xv[rr] - sn;
            }
        }
    }
}

extern "C" void kernel_launch(void* const* d_in, const int* in_sizes, int n_in,
                              void* d_out, int out_size, void* d_ws, size_t ws_size,
                              hipStream_t stream) {
    const float* x    = (const float*)d_in[0];
    const float* w    = (const float*)d_in[1];
    const float* bias = (const float*)d_in[2];
    float* out = (float*)d_out;

    const int C = in_sizes[2];              // 4096
    const int D = in_sizes[1] / C;          // 1024
    const int B = in_sizes[0] / D;          // 8192

    unsigned char* x8 = (unsigned char*)d_ws;              // B*D fp8 = 8 MB
    unsigned char* c8 = x8 + (size_t)B * D;                // C*D fp8 = 4 MB
    float* x2 = (float*)(c8 + (size_t)C * D);              // B fp32
    float* s  = x2 + B;                                    // C fp32

    init_s<<<(C + 255) / 256, 256, 0, stream>>>(bias, s, C);
    prep_w<<<dim3(D / 64, C / 64), 256, 0, stream>>>(w, c8, s);
    prep_x<<<B, 256, 0, stream>>>(x, (unsigned int*)x8, x2);
    const int nblocks = (B / TM) * (C / TN);
    gemm_bt<<<nblocks, 256, 0, stream>>>(x8, c8, x2, s, out, B, C, D);
}

// Round 5
// 199.302 us; speedup vs baseline: 1.3039x; 1.0230x over previous
//
#include <hip/hip_runtime.h>

#define TM 128
#define TN 256
#define BK 128   // fp8 bytes per K-slab = one 16x16x128 MFMA k-step

typedef float f32x4 __attribute__((ext_vector_type(4)));
typedef int   i32x4 __attribute__((ext_vector_type(4)));
typedef int   i32x8 __attribute__((ext_vector_type(8)));

// E8M0 scales: value = 2^(byte-127). A-scale = 2^0; B holds cent*2^6, B-scale = 2^-6.
#define SCALE_A 127
#define SCALE_B 121

__device__ __forceinline__ unsigned char f2fp8(float f) {
    int p = __builtin_amdgcn_cvt_pk_fp8_f32(f, f, 0, false);
    return (unsigned char)(p & 0xff);
}

// ---- prep_x: x (B,1024) fp32 -> x8 fp8 row-major, x2[b] = sum(x^2) (exact fp32) ----
__global__ __launch_bounds__(256) void prep_x(const float* __restrict__ x,
                                              unsigned int* __restrict__ x8,
                                              float* __restrict__ x2) {
    const int b = blockIdx.x;
    const int t = threadIdx.x;
    const float4 v = ((const float4*)(x + (size_t)b * 1024))[t];
    float sum = v.x * v.x + v.y * v.y + v.z * v.z + v.w * v.w;
    int p = __builtin_amdgcn_cvt_pk_fp8_f32(v.x, v.y, 0, false);
    p = __builtin_amdgcn_cvt_pk_fp8_f32(v.z, v.w, p, true);
    x8[(size_t)b * 256 + t] = (unsigned int)p;
    #pragma unroll
    for (int o = 32; o > 0; o >>= 1) sum += __shfl_down(sum, o, 64);
    __shared__ float red[4];
    if ((t & 63) == 0) red[t >> 6] = sum;
    __syncthreads();
    if (t == 0) x2[b] = red[0] + red[1] + red[2] + red[3];
}

// ---- init_s: s[c] = bias[c] (c2 accumulated atomically by prep_w) ----
__global__ __launch_bounds__(256) void init_s(const float* __restrict__ bias,
                                              float* __restrict__ s, int C) {
    int i = blockIdx.x * 256 + threadIdx.x;
    if (i < C) s[i] = bias[i];
}

// ---- prep_w: cent[4q+r][d] = W[r*1024+d][q]; c8 = fp8(cent*64) (C x D row-major);
//      s[c] += ||cent_c||^2 (exact fp32, from fp32 W). LDS-tiled transpose. ----
__global__ __launch_bounds__(256) void prep_w(const float* __restrict__ W,
                                              unsigned char* __restrict__ c8,
                                              float* __restrict__ s) {
    __shared__ float tile[64][65];
    __shared__ float cred[4][64];
    const int tid = threadIdx.x;
    const int tx = tid & 63;
    const int ty = tid >> 6;
    const int q0 = blockIdx.x * 64;
    const int e0 = blockIdx.y * 64;      // e = r*1024 + d
    const int r  = e0 >> 10;
    const int d0 = e0 & 1023;

    float csum = 0.f;
    #pragma unroll
    for (int p = 0; p < 16; p++) {
        const int er = p * 4 + ty;
        const float v = W[(size_t)(e0 + er) * 1024 + q0 + tx];
        tile[er][tx] = v;
        csum += v * v;
    }
    cred[ty][tx] = csum;
    __syncthreads();
    if (ty == 0) {
        atomicAdd(&s[4 * (q0 + tx) + r],
                  cred[0][tx] + cred[1][tx] + cred[2][tx] + cred[3][tx]);
    }
    #pragma unroll
    for (int p = 0; p < 16; p++) {
        const int q = q0 + p * 4 + ty;
        const float v = tile[tx][p * 4 + ty];
        c8[(size_t)(4 * q + r) * 1024 + d0 + tx] = f2fp8(v * 64.f);
    }
}

// ---- gemm_bt: out[m][n] = 2*sum_k A[m][k]*Bt[n][k] - x2[m] - s[n] ----
// MX-scaled fp8 16x16x128. Block tile 128x256, 4 waves, EACH WAVE OWNS 64x128
// (4x8 MFMA tiles) -> 32 MFMA per slab per wave: 2x the per-wave ILP of R4's
// 64x64, amortizing barrier/LDS latency inside the wave instead of relying on
// occupancy (which R4 showed doesn't help). Single 48 KB LDS buffer, 2-barrier
// K-loop (R4 proved dbuf neutral). XOR-swizzled chunks (0 conflicts, verified).
// XCD m-stripe swizzle: xcd owns 8 m-tiles (1 MB A-stripe resident in its L2).
__global__ __launch_bounds__(256, 2) void gemm_bt(const unsigned char* __restrict__ A,
                                                  const unsigned char* __restrict__ Bt,
                                                  const float* __restrict__ x2,
                                                  const float* __restrict__ s,
                                                  float* __restrict__ out,
                                                  int M, int N, int K) {
    __shared__ unsigned char la[TM * BK];   // 16 KB
    __shared__ unsigned char lb[TN * BK];   // 32 KB

    const int tid  = threadIdx.x;
    const int wave = tid >> 6;
    const int lane = tid & 63;
    const int quad = lane >> 4;
    const int l16  = lane & 15;
    const int wm   = wave & 1;     // m half: 64 rows
    const int wn   = wave >> 1;    // n half: 128 cols

    // XCD m-stripe swizzle (m-tiles = M/TM = 64, n-tiles = N/TN = 16)
    const int flat = blockIdx.x;
    const int xcd  = flat & 7;
    const int idx  = flat >> 3;
    const int mt   = (idx & 7) | (xcd << 3);
    const int nt   = idx >> 3;
    const int tile_m = mt * TM;
    const int tile_n = nt * TN;

    // staging: lane -> row (base + lane/8), slot (lane&7); source chunk XOR-swizzled
    const int srow8 = lane >> 3;
    const int gcol  = ((lane & 7) ^ srow8) * 16;
    const unsigned char* gA = A  + (size_t)(tile_m + wave * 32 + srow8) * K + gcol;
    const unsigned char* gB = Bt + (size_t)(tile_n + wave * 64 + srow8) * K + gcol;

    f32x4 acc[4][8];
    #pragma unroll
    for (int i = 0; i < 4; i++)
        #pragma unroll
        for (int j = 0; j < 8; j++) acc[i][j] = (f32x4){0.f, 0.f, 0.f, 0.f};

    const int sw = l16 & 7;
    const int slot_lo = ((2 * quad) ^ sw) * 16;
    const int slot_hi = ((2 * quad + 1) ^ sw) * 16;
    const unsigned char* pa_row = la + (wm * 64 + l16) * BK;
    const unsigned char* pb_row = lb + (wn * 128 + l16) * BK;

    for (int kt = 0; kt < K; kt += BK) {
        __syncthreads();
        // A: wave stages rows [wave*32, wave*32+32); B: rows [wave*64, wave*64+64)
        #pragma unroll
        for (int i = 0; i < 4; i++) {
            __builtin_amdgcn_global_load_lds(
                (const __attribute__((address_space(1))) void*)(gA + (size_t)(i * 8) * K + kt),
                (__attribute__((address_space(3))) void*)(la + (wave * 32 + i * 8) * BK),
                16, 0, 0);
        }
        #pragma unroll
        for (int j = 0; j < 8; j++) {
            __builtin_amdgcn_global_load_lds(
                (const __attribute__((address_space(1))) void*)(gB + (size_t)(j * 8) * K + kt),
                (__attribute__((address_space(3))) void*)(lb + (wave * 64 + j * 8) * BK),
                16, 0, 0);
        }
        __syncthreads();

        i32x8 af[4];
        #pragma unroll
        for (int i = 0; i < 4; i++) {
            i32x4 lo = *(const i32x4*)(pa_row + i * 16 * BK + slot_lo);
            i32x4 hi = *(const i32x4*)(pa_row + i * 16 * BK + slot_hi);
            af[i] = __builtin_shufflevector(lo, hi, 0, 1, 2, 3, 4, 5, 6, 7);
        }
        #pragma unroll
        for (int j = 0; j < 8; j++) {
            i32x4 lo = *(const i32x4*)(pb_row + j * 16 * BK + slot_lo);
            i32x4 hi = *(const i32x4*)(pb_row + j * 16 * BK + slot_hi);
            i32x8 bf = __builtin_shufflevector(lo, hi, 0, 1, 2, 3, 4, 5, 6, 7);
            #pragma unroll
            for (int i = 0; i < 4; i++)
                acc[i][j] = __builtin_amdgcn_mfma_scale_f32_16x16x128_f8f6f4(
                    af[i], bf, acc[i][j], 0, 0, 0, SCALE_A, 0, SCALE_B);
        }
    }

    // epilogue: C/D layout col = lane&15, row = quad*4 + reg
    f32x4 xv[4];
    #pragma unroll
    for (int i = 0; i < 4; i++)
        xv[i] = *(const f32x4*)(x2 + tile_m + wm * 64 + i * 16 + quad * 4);
    #pragma unroll
    for (int j = 0; j < 8; j++) {
        const int n = tile_n + wn * 128 + j * 16 + l16;
        const float sn = s[n];
        #pragma unroll
        for (int i = 0; i < 4; i++) {
            const int mb = tile_m + wm * 64 + i * 16 + quad * 4;
            #pragma unroll
            for (int rr = 0; rr < 4; rr++) {
                out[(size_t)(mb + rr) * N + n] = 2.f * acc[i][j][rr] - xv[i][rr] - sn;
            }
        }
    }
}

extern "C" void kernel_launch(void* const* d_in, const int* in_sizes, int n_in,
                              void* d_out, int out_size, void* d_ws, size_t ws_size,
                              hipStream_t stream) {
    const float* x    = (const float*)d_in[0];
    const float* w    = (const float*)d_in[1];
    const float* bias = (const float*)d_in[2];
    float* out = (float*)d_out;

    const int C = in_sizes[2];              // 4096
    const int D = in_sizes[1] / C;          // 1024
    const int B = in_sizes[0] / D;          // 8192

    unsigned char* x8 = (unsigned char*)d_ws;              // B*D fp8 = 8 MB
    unsigned char* c8 = x8 + (size_t)B * D;                // C*D fp8 = 4 MB
    float* x2 = (float*)(c8 + (size_t)C * D);              // B fp32
    float* s  = x2 + B;                                    // C fp32

    init_s<<<(C + 255) / 256, 256, 0, stream>>>(bias, s, C);
    prep_w<<<dim3(D / 64, C / 64), 256, 0, stream>>>(w, c8, s);
    prep_x<<<B, 256, 0, stream>>>(x, (unsigned int*)x8, x2);
    const int nblocks = (B / TM) * (C / TN);
    gemm_bt<<<nblocks, 256, 0, stream>>>(x8, c8, x2, s, out, B, C, D);
}